// Round 14
// baseline (350.495 us; speedup 1.0000x reference)
//
#include <hip/hip_runtime.h>
#include <cstdint>
#include <cstddef>

// DinoDecoderBlock on MI355X (gfx950).
// B=4 NQ=NK=1024 C=768 H=12 DH=64, scale=1/8, eps=1e-5.
// R14: (1) defer ln(y) + 7 weight cvts as aux tails on D2/D3 (prep_k -> 8us);
//      (2) bias tails rebalanced by carrier compute cover (800/800/1700/796);
//      (3) fattn<1> bias restaged per-wave via LDS (full-cacheline reads).

typedef __bf16 bf16;
typedef __attribute__((ext_vector_type(8))) __bf16 bf16x8;
typedef __attribute__((ext_vector_type(4))) __bf16 bf16x4;
typedef __attribute__((ext_vector_type(4))) float f32x4;

typedef __attribute__((address_space(1))) void gvoid;
typedef __attribute__((address_space(3))) void lvoid;

#define DEVI static __device__ __forceinline__

DEVI void gload16(const void* g, void* l) {
  __builtin_amdgcn_global_load_lds((gvoid*)(uintptr_t)g, (lvoid*)(uintptr_t)l, 16, 0, 0);
}

DEVI f32x4 mfma_bf16(bf16x8 a, bf16x8 b, f32x4 c) {
  return __builtin_amdgcn_mfma_f32_16x16x32_bf16(a, b, c, 0, 0, 0);
}

// ================= device bodies =================

// ---- GEMM tile body ----
template<int BM, int BN, bool BIAS, bool GELU, bool RES, bool OBF, bool VT>
DEVI void gemm_dev(bf16* As, bf16* Bs, int by, int bx,
                   const bf16* __restrict__ A, const bf16* __restrict__ Bt,
                   const float* __restrict__ bias, const float* __restrict__ res,
                   bf16* __restrict__ Cb, float* __restrict__ Cf,
                   bf16* __restrict__ vtOut, int vtBase, int N, int K)
{
  constexpr int WM = BM / 2, WN = BN / 2;
  constexpr int FM = WM / 16, FN = WN / 16;
  const int tid = threadIdx.x;
  const int lane = tid & 63;
  const int wv = tid >> 6;
  const int wr = wv >> 1, wc = wv & 1;
  const int l15 = lane & 15, lg = lane >> 4;
  const int bm = by * BM, bn = bx * BN;

  f32x4 acc[FM][FN];
  const f32x4 z = {0.f, 0.f, 0.f, 0.f};
  #pragma unroll
  for (int i = 0; i < FM; ++i)
    #pragma unroll
    for (int jj = 0; jj < FN; ++jj) acc[i][jj] = z;

  for (int k0 = 0; k0 < K; k0 += 64) {
    __syncthreads();
    #pragma unroll
    for (int c = tid; c < BM * 8; c += 256) {
      const int row = c >> 3, colb = (c & 7) << 4;
      gload16((const char*)A + ((size_t)(bm + row) * K + k0) * 2 + colb,
              (char*)As + (size_t)c * 16);
    }
    #pragma unroll
    for (int c = tid; c < BN * 8; c += 256) {
      const int row = c >> 3, colb = (c & 7) << 4;
      gload16((const char*)Bt + ((size_t)(bn + row) * K + k0) * 2 + colb,
              (char*)Bs + (size_t)c * 16);
    }
    __syncthreads();
    #pragma unroll
    for (int kk = 0; kk < 64; kk += 32) {
      bf16x8 af[FM], bfr[FN];
      #pragma unroll
      for (int mi = 0; mi < FM; ++mi)
        af[mi] = *(const bf16x8*)(As + (size_t)(wr * WM + mi * 16 + l15) * 64 + kk + lg * 8);
      #pragma unroll
      for (int ni = 0; ni < FN; ++ni)
        bfr[ni] = *(const bf16x8*)(Bs + (size_t)(wc * WN + ni * 16 + l15) * 64 + kk + lg * 8);
      #pragma unroll
      for (int mi = 0; mi < FM; ++mi)
        #pragma unroll
        for (int ni = 0; ni < FN; ++ni)
          acc[mi][ni] = mfma_bf16(af[mi], bfr[ni], acc[mi][ni]);
    }
  }

  #pragma unroll
  for (int mi = 0; mi < FM; ++mi) {
    const int row0 = bm + wr * WM + mi * 16 + lg * 4;
    #pragma unroll
    for (int ni = 0; ni < FN; ++ni) {
      const int col = bn + wc * WN + ni * 16 + l15;
      if constexpr (VT) {
        if (col >= vtBase) {   // V channel: store transposed, 4 consecutive n
          const int hd = col - vtBase;            // h*64+d
          const int bb = row0 >> 10, n0 = row0 & 1023;
          bf16x4 ov;
          #pragma unroll
          for (int r = 0; r < 4; ++r) ov[r] = (bf16)acc[mi][ni][r];
          *(bf16x4*)(vtOut + ((size_t)(bb * 768 + hd)) * 1024 + n0) = ov;
          continue;
        }
      }
      #pragma unroll
      for (int r = 0; r < 4; ++r) {
        float v = acc[mi][ni][r];
        if constexpr (BIAS) v += bias[col];
        if constexpr (GELU) v = 0.5f * v * (1.0f + erff(v * 0.70710678118654752f));
        if constexpr (RES)  v += res[(size_t)(row0 + r) * N + col];
        if constexpr (OBF)  Cb[(size_t)(row0 + r) * N + col] = (bf16)v;
        else                Cf[(size_t)(row0 + r) * N + col] = v;
      }
    }
  }
}

// ---- register bias body: one (b,q) per block; out[b][q][h][k] ----
DEVI void biasr_dev(int blk,
                    const float* __restrict__ sim,
                    const unsigned char* __restrict__ mask,
                    bf16* __restrict__ out)
{
  const int b = blk >> 10, q = blk & 1023;
  const int t = threadIdx.x, lane = t & 63;

  // mask dtype detect per wave (1KB window): int32 0/1 has zero non-LSB bytes
  int ds = 0;
  #pragma unroll
  for (int i = 0; i < 4; ++i) {
    const int idx = (lane * 4 + i) * 4;
    ds += mask[idx + 1] + mask[idx + 2] + mask[idx + 3];
  }
  #pragma unroll
  for (int o = 32; o; o >>= 1) ds += __shfl_xor(ds, o);
  const int msh = (ds == 0) ? 2 : 0;

  const int k4 = t * 4;
  const float* sb = sim + (size_t)b * 12 * 1048576;
  f32x4 sv[12];
  f32x4 acc = {0.f, 0.f, 0.f, 0.f};
  #pragma unroll
  for (int h = 0; h < 12; ++h) {
    sv[h] = *(const f32x4*)(sb + ((size_t)h * 1024 + q) * 1024 + k4);
    acc += sv[h];
  }
  const f32x4 mean = acc * (1.0f / 12.0f);

  float mb[4];
  if (msh == 0) {
    const uchar4 mv = *(const uchar4*)(mask + (size_t)q * 1024 + k4);
    mb[0] = mv.x ? 0.f : -1e30f; mb[1] = mv.y ? 0.f : -1e30f;
    mb[2] = mv.z ? 0.f : -1e30f; mb[3] = mv.w ? 0.f : -1e30f;
  } else {
    const int4 mv = *(const int4*)((const int*)mask + (size_t)q * 1024 + k4);
    mb[0] = mv.x ? 0.f : -1e30f; mb[1] = mv.y ? 0.f : -1e30f;
    mb[2] = mv.z ? 0.f : -1e30f; mb[3] = mv.w ? 0.f : -1e30f;
  }

  bf16* ob = out + (size_t)(b * 1024 + q) * 12 * 1024;
  #pragma unroll
  for (int h = 0; h < 12; ++h) {
    bf16x4 o;
    #pragma unroll
    for (int j = 0; j < 4; ++j)
      o[j] = (bf16)(sv[h][j] - mean[j] + mb[j]);
    *(bf16x4*)(ob + h * 1024 + k4) = o;
  }
}

// ---- wave-parallel LayerNorm: one wave = one row of 768 ----
DEVI void lnw_dev(int row,
                  const float* __restrict__ xin, const float* __restrict__ g,
                  const float* __restrict__ be, bf16* __restrict__ out)
{
  const int lane = threadIdx.x & 63;
  const f32x4* xr = (const f32x4*)(xin + (size_t)row * 768);
  f32x4 v[3];
  #pragma unroll
  for (int j = 0; j < 3; ++j) v[j] = xr[lane + 64 * j];
  float s = 0.f;
  #pragma unroll
  for (int j = 0; j < 3; ++j) s += v[j][0] + v[j][1] + v[j][2] + v[j][3];
  #pragma unroll
  for (int o = 32; o; o >>= 1) s += __shfl_xor(s, o);
  const float mean = s * (1.0f / 768.0f);
  float q = 0.f;
  #pragma unroll
  for (int j = 0; j < 3; ++j)
    #pragma unroll
    for (int e = 0; e < 4; ++e) { const float d = v[j][e] - mean; q += d * d; }
  #pragma unroll
  for (int o = 32; o; o >>= 1) q += __shfl_xor(q, o);
  const float inv = rsqrtf(q * (1.0f / 768.0f) + 1e-5f);
  #pragma unroll
  for (int j = 0; j < 3; ++j) {
    const int c = lane + 64 * j;
    const f32x4 gv = ((const f32x4*)g)[c];
    const f32x4 bv = ((const f32x4*)be)[c];
    bf16x4 o4;
    #pragma unroll
    for (int e = 0; e < 4; ++e)
      o4[e] = (bf16)((v[j][e] - mean) * inv * gv[e] + bv[e]);
    *((bf16x4*)out + (size_t)row * 192 + c) = o4;
  }
}

// ---- aux tail work: extra space = [0,1024) ln(y) rows, [1024,..) deferred cvt
struct AuxArgs {
  const float* csrc[7];
  bf16* cdst[7];
  int cend[7];                // cumulative f32x4 counts
  const float* y; const float* gy; const float* byv; bf16* yln;
  const float* sim; const unsigned char* mask; bf16* biasOut;
  int biasStart, biasCount, extraStart, extraCount;
};

DEVI void aux_dev(int j, const AuxArgs& A)
{
  if (j < A.extraCount) {
    const int e = A.extraStart + j;
    if (e < 1024) {
      lnw_dev(e * 4 + (threadIdx.x >> 6), A.y, A.gy, A.byv, A.yln);
    } else {
      const int blk = e - 1024;
      const int t = threadIdx.x;
      #pragma unroll
      for (int u = 0; u < 4; ++u) {
        const int i = blk * 1024 + u * 256 + t;
        int s = 0;
        #pragma unroll
        for (int k = 0; k < 6; ++k) s += (i >= A.cend[k]) ? 1 : 0;
        const int base = s ? A.cend[s - 1] : 0;
        const int off = i - base;
        const f32x4 v = *((const f32x4*)A.csrc[s] + off);
        bf16x4 o;
        o[0] = (bf16)v[0]; o[1] = (bf16)v[1]; o[2] = (bf16)v[2]; o[3] = (bf16)v[3];
        *(bf16x4*)(A.cdst[s] + (size_t)off * 4) = o;
      }
    }
  } else {
    biasr_dev(A.biasStart + (j - A.extraCount), A.sim, A.mask, A.biasOut);
  }
}

// ================= kernels =================

// D1: qkv weight cvt [0,432) + ln(x) [432,1456)
__global__ __launch_bounds__(256)
void prep_k(const float* __restrict__ qkvw, bf16* __restrict__ w_qkv,
            const float* __restrict__ x, const float* __restrict__ g1,
            const float* __restrict__ b1, bf16* __restrict__ xn)
{
  const int f = blockIdx.x;
  const int t = threadIdx.x;
  if (f < 432) {
    #pragma unroll
    for (int u = 0; u < 4; ++u) {
      const int i = f * 1024 + u * 256 + t;
      const f32x4 v = *((const f32x4*)qkvw + i);
      bf16x4 o;
      o[0] = (bf16)v[0]; o[1] = (bf16)v[1]; o[2] = (bf16)v[2]; o[3] = (bf16)v[3];
      *(bf16x4*)(w_qkv + (size_t)i * 4) = o;
    }
  } else {
    lnw_dev((f - 432) * 4 + (t >> 6), x, g1, b1, xn);
  }
}

// GEMM wrapper with aux tail
template<int BM, int BN, bool BIAS, bool GELU, bool RES, bool OBF, bool VT>
__global__ __launch_bounds__(256)
void gemm_bt(const bf16* __restrict__ A, const bf16* __restrict__ Bt,
             const float* __restrict__ bias, const float* __restrict__ res,
             bf16* __restrict__ Cb, float* __restrict__ Cf,
             bf16* __restrict__ vtOut, int vtBase,
             int nyPerXcd, int N, int K,
             int nCompute, AuxArgs aux)
{
  __shared__ bf16 As[BM * 64];
  __shared__ bf16 Bs[BN * 64];
  const int f = blockIdx.x;
  if (f >= nCompute) {
    aux_dev(f - nCompute, aux);
    return;
  }
  const int xcd = f & 7, j = f >> 3;
  const int by = xcd + 8 * (j % nyPerXcd);
  const int bx = j / nyPerXcd;
  gemm_dev<BM,BN,BIAS,GELU,RES,OBF,VT>(As, Bs, by, bx,
      A, Bt, bias, res, Cb, Cf, vtOut, vtBase, N, K);
}

// aproj (0..383) + pkv (384..767) + aux tail
__global__ __launch_bounds__(256)
void apkv_k(const bf16* __restrict__ sa, const bf16* __restrict__ w_ap,
            const float* __restrict__ apb, const float* __restrict__ x,
            float* __restrict__ x1,
            const bf16* __restrict__ yln, const bf16* __restrict__ w_pkv,
            bf16* __restrict__ ckv, bf16* __restrict__ cvtT,
            AuxArgs aux)
{
  __shared__ bf16 As[128 * 64];
  __shared__ bf16 Bs[128 * 64];
  const int f = blockIdx.x;
  if (f >= 768) {
    aux_dev(f - 768, aux);
    return;
  }
  if (f < 384) {
    const int xcd = f & 7, j = f >> 3;
    const int by = xcd + 8 * (j % 8);
    const int bx = j / 8;
    gemm_dev<64,128,true,false,true,false,false>(As, Bs, by, bx,
        sa, w_ap, apb, x, nullptr, x1, nullptr, 0, 768, 768);
  } else {
    const int g = f - 384;
    const int xcd = g & 7, j = g >> 3;
    const int by = xcd + 8 * (j % 4);
    const int bx = j / 4;
    gemm_dev<128,128,false,false,false,true,true>(As, Bs, by, bx,
        yln, w_pkv, nullptr, nullptr, ckv, nullptr, cvtT, 768, 1536, 768);
  }
}

// fc2 (0..383) + y-copy (384..895, grid-stride)
__global__ __launch_bounds__(256)
void fc2copy_k(const bf16* __restrict__ hbuf, const bf16* __restrict__ w_f2,
               const float* __restrict__ f2b, const float* __restrict__ x2,
               float* __restrict__ outp,
               const float* __restrict__ y, float* __restrict__ ycopy)
{
  __shared__ bf16 As[128 * 64];
  __shared__ bf16 Bs[128 * 64];
  const int f = blockIdx.x;
  if (f < 384) {
    const int xcd = f & 7, j = f >> 3;
    const int by = xcd + 8 * (j % 8);
    const int bx = j / 8;
    gemm_dev<64,128,true,false,true,false,false>(As, Bs, by, bx,
        hbuf, w_f2, f2b, x2, nullptr, outp, nullptr, 0, 768, 3072);
  } else {
    for (int i = (f - 384) * 256 + threadIdx.x; i < 786432; i += 512 * 256)
      ((f32x4*)ycopy)[i] = ((const f32x4*)y)[i];
  }
}

// standalone LayerNorm (ln2 / ln3): 4 rows/block, wave-parallel
__global__ __launch_bounds__(256)
void ln_k(const float* __restrict__ xin, const float* __restrict__ g,
          const float* __restrict__ be, bf16* __restrict__ out)
{
  lnw_dev(blockIdx.x * 4 + (threadIdx.x >> 6), xin, g, be, out);
}

// ---------------- flash attention: 64 q-rows/block, 4 waves, online softmax ----
// CROSS: bias layout [b][q][h][k]; bias restaged per-wave via LDS
// (lane reads 32B contiguous, 4 lanes/row -> full 128B lines).
template<int CROSS>
__global__ __launch_bounds__(256, 3)
void fattn_k(const bf16* __restrict__ Qp, int ldq,
             const bf16* __restrict__ Kp, int ldk,
             const bf16* __restrict__ Vt,
             const bf16* __restrict__ bias,
             bf16* __restrict__ Out,
             int nCompute, AuxArgs aux)
{
  __shared__ bf16 Kl[2][64 * 64];     // 16 KB, [krow][c] swizzled
  __shared__ bf16 Vl[2][64 * 64];     // 16 KB, [d][k]   swizzled
  __shared__ bf16 Pl[4][16 * 72];     // per-wave P tile, padded
  __shared__ bf16 Bl[CROSS ? 4 * 16 * 72 : 4];  // per-wave bias tile, padded

  const int f = blockIdx.x;
  if (f >= nCompute) {
    aux_dev(f - nCompute, aux);
    return;
  }
  const int r8 = f & 7, rest = f >> 3;
  const int c6 = rest % 6, qt = rest / 6;
  const int pp = r8 + 8 * c6;          // 0..47
  const int b = pp / 12, hh = pp % 12;
  const int tid = threadIdx.x, lane = tid & 63, wq = tid >> 6;
  const int l15 = lane & 15, lg = lane >> 4;

  bf16x8 qreg0, qreg1;
  {
    const bf16* qsrc = Qp + (size_t)(b * 1024 + qt * 64 + wq * 16 + l15) * ldq + hh * 64 + lg * 8;
    qreg0 = *(const bf16x8*)qsrc;
    qreg1 = *(const bf16x8*)(qsrc + 32);
  }
  const char* Kbase = (const char*)(Kp + (size_t)b * 1024 * ldk + hh * 64);
  const char* Vbase = (const char*)(Vt + (size_t)(b * 12 + hh) * 64 * 1024);
  const bf16* biasQ = nullptr;
  if constexpr (CROSS)   // [b][q][h][k]: lane covers row qbase+(lane>>2), 32B chunk (lane&3)
    biasQ = bias + ((size_t)(b * 1024 + qt * 64 + wq * 16 + (lane >> 2)) * 12 + hh) * 1024
          + (lane & 3) * 16;

  f32x4 oacc[4];
  const f32x4 z = {0.f, 0.f, 0.f, 0.f};
  #pragma unroll
  for (int i = 0; i < 4; ++i) oacc[i] = z;
  float m_run = -1e30f, l_run = 0.f;

  char* PlW = (char*)&Pl[wq][0];
  char* BlW = (char*)&Bl[0] + (CROSS ? wq * 16 * 144 : 0);
  const int swz = (l15 & 7) << 4;      // read-side XOR (row&7)<<4

  auto stage = [&](int buf, int t) {
    const int k0 = t * 64;
    #pragma unroll
    for (int jj = 0; jj < 2; ++jj) {
      const int c = jj * 256 + tid;                // 16B chunk id 0..511
      const int r = c >> 3;
      const int sw = ((c & 7) ^ (r & 7)) << 4;     // swizzled byte-col in row
      gload16(Kbase + ((size_t)(k0 + r) * ldk) * 2 + sw, (char*)&Kl[buf][0] + (size_t)c * 16);
      gload16(Vbase + (size_t)r * 2048 + (size_t)k0 * 2 + sw, (char*)&Vl[buf][0] + (size_t)c * 16);
    }
  };

  stage(0, 0);
  __syncthreads();   // prologue staging drained

  for (int t = 0; t < 16; ++t) {
    const int cur = t & 1;
    const int k0 = t * 64;

    // issue bias reads early (32B/lane, coalesced into 128B lines)
    bf16x8 br0, br1;
    if constexpr (CROSS) {
      const bf16* bp = biasQ + k0;
      br0 = *(const bf16x8*)bp;
      br1 = *(const bf16x8*)(bp + 8);
    }
    if (t < 15) stage(cur ^ 1, t + 1);   // async prefetch; drained at loop-end barrier

    // ---- S^T = K . Q^T ----
    f32x4 sacc[4];
    #pragma unroll
    for (int i = 0; i < 4; ++i) sacc[i] = z;
    #pragma unroll
    for (int ni = 0; ni < 4; ++ni) {
      const int rowb = (ni * 16 + l15) * 128;
      const bf16x8 a0 = *(const bf16x8*)((char*)&Kl[cur][0] + rowb + ((lg * 16) ^ swz));
      const bf16x8 a1 = *(const bf16x8*)((char*)&Kl[cur][0] + rowb + ((64 + lg * 16) ^ swz));
      sacc[ni] = mfma_bf16(a0, qreg0, sacc[ni]);
      sacc[ni] = mfma_bf16(a1, qreg1, sacc[ni]);
    }

    // ---- bias via per-wave LDS redistribute (same-wave write->read, like Pl) ----
    bf16x4 bv[4];
    if constexpr (CROSS) {
      char* dst = BlW + (lane >> 2) * 144 + (lane & 3) * 32;
      *(bf16x8*)dst = br0;
      *(bf16x8*)(dst + 16) = br1;
      #pragma unroll
      for (int ni = 0; ni < 4; ++ni)
        bv[ni] = *(const bf16x4*)(BlW + l15 * 144 + ni * 32 + lg * 8);
    }

    // ---- online softmax ----
    float sv[16];
    #pragma unroll
    for (int ni = 0; ni < 4; ++ni)
      #pragma unroll
      for (int r = 0; r < 4; ++r)
        sv[ni * 4 + r] = sacc[ni][r] * 0.125f;
    if constexpr (CROSS) {
      #pragma unroll
      for (int ni = 0; ni < 4; ++ni)
        #pragma unroll
        for (int r = 0; r < 4; ++r)
          sv[ni * 4 + r] += (float)bv[ni][r];
    }
    float mx = sv[0];
    #pragma unroll
    for (int jj = 1; jj < 16; ++jj) mx = fmaxf(mx, sv[jj]);
    mx = fmaxf(mx, __shfl_xor(mx, 16));
    mx = fmaxf(mx, __shfl_xor(mx, 32));
    const float mnew = fmaxf(m_run, mx);
    const float corr = __expf(m_run - mnew);
    m_run = mnew;
    float ps = 0.f;
    #pragma unroll
    for (int jj = 0; jj < 16; ++jj) { sv[jj] = __expf(sv[jj] - mnew); ps += sv[jj]; }
    l_run = l_run * corr + ps;

    // ---- P -> per-wave LDS (fragment-layout transpose) ----
    #pragma unroll
    for (int ni = 0; ni < 4; ++ni) {
      bf16x4 pw;
      #pragma unroll
      for (int r = 0; r < 4; ++r) pw[r] = (bf16)sv[ni * 4 + r];
      *(bf16x4*)(PlW + l15 * 144 + ni * 32 + lg * 8) = pw;
    }
    float cr[4];
    #pragma unroll
    for (int r = 0; r < 4; ++r) cr[r] = __shfl(corr, ((lane >> 4) << 2) + r);
    #pragma unroll
    for (int nd = 0; nd < 4; ++nd)
      #pragma unroll
      for (int r = 0; r < 4; ++r) oacc[nd][r] *= cr[r];

    // ---- O += P . V ----
    const bf16x8 p0 = *(const bf16x8*)(PlW + l15 * 144 + lg * 16);
    const bf16x8 p1 = *(const bf16x8*)(PlW + l15 * 144 + 64 + lg * 16);
    #pragma unroll
    for (int nd = 0; nd < 4; ++nd) {
      const int rowb = (nd * 16 + l15) * 128;
      const bf16x8 v0 = *(const bf16x8*)((char*)&Vl[cur][0] + rowb + ((lg * 16) ^ swz));
      const bf16x8 v1 = *(const bf16x8*)((char*)&Vl[cur][0] + rowb + ((64 + lg * 16) ^ swz));
      oacc[nd] = mfma_bf16(p0, v0, oacc[nd]);
      oacc[nd] = mfma_bf16(p1, v1, oacc[nd]);
    }
    __syncthreads();   // staging t+1 complete; all waves done with buf cur
  }

  // ---- finalize ----
  float ls = l_run + __shfl_xor(l_run, 16);
  ls += __shfl_xor(ls, 32);
  const float inv = 1.0f / ls;
  float ivr[4];
  #pragma unroll
  for (int r = 0; r < 4; ++r) ivr[r] = __shfl(inv, ((lane >> 4) << 2) + r);
  bf16* ob = Out + (size_t)(b * 1024 + qt * 64 + wq * 16 + lg * 4) * 768 + hh * 64 + l15;
  #pragma unroll
  for (int r = 0; r < 4; ++r)
    #pragma unroll
    for (int nd = 0; nd < 4; ++nd)
      ob[(size_t)r * 768 + nd * 16] = (bf16)(oacc[nd][r] * ivr[r]);
}

// ---------------- launcher ----------------
extern "C" void kernel_launch(void* const* d_in, const int* in_sizes, int n_in,
                              void* d_out, int out_size, void* d_ws, size_t ws_size,
                              hipStream_t stream)
{
  (void)in_sizes; (void)n_in; (void)out_size; (void)ws_size;
  const float* x    = (const float*)d_in[0];
  const float* y    = (const float*)d_in[1];
  const unsigned char* mask = (const unsigned char*)d_in[4];
  const float* sim  = (const float*)d_in[5];
  const float* ln1g = (const float*)d_in[6];
  const float* ln1b = (const float*)d_in[7];
  const float* ln2g = (const float*)d_in[8];
  const float* ln2b = (const float*)d_in[9];
  const float* ln3g = (const float*)d_in[10];
  const float* ln3b = (const float*)d_in[11];
  const float* lnyg = (const float*)d_in[12];
  const float* lnyb = (const float*)d_in[13];
  const float* qkvw = (const float*)d_in[14];
  const float* apw  = (const float*)d_in[15];
  const float* apb  = (const float*)d_in[16];
  const float* pqw  = (const float*)d_in[17];
  const float* pkw  = (const float*)d_in[18];
  const float* pvw  = (const float*)d_in[19];
  const float* cpw  = (const float*)d_in[20];
  const float* cpb  = (const float*)d_in[21];
  const float* f1w  = (const float*)d_in[22];
  const float* f1b  = (const float*)d_in[23];
  const float* f2w  = (const float*)d_in[24];
  const float* f2b  = (const float*)d_in[25];

  char* ws = (char*)d_ws;
  size_t off = 0;
  auto alloc = [&](size_t bytes) -> void* {
    off = (off + 255) & ~(size_t)255;
    void* p = ws + off;
    off += bytes;
    return p;
  };
  const size_t T = 4096;  // B*NQ
  bf16* w_qkv = (bf16*)alloc((size_t)2304 * 768 * 2);
  bf16* w_ap  = (bf16*)alloc((size_t)768 * 768 * 2);
  bf16* w_pq  = (bf16*)alloc((size_t)768 * 768 * 2);
  bf16* w_pkv = (bf16*)alloc((size_t)1536 * 768 * 2);
  bf16* w_cp  = (bf16*)alloc((size_t)768 * 768 * 2);
  bf16* w_f1  = (bf16*)alloc((size_t)3072 * 768 * 2);
  bf16* w_f2  = (bf16*)alloc((size_t)768 * 3072 * 2);
  bf16* xn    = (bf16*)alloc(T * 768 * 2);
  bf16* qkvo  = (bf16*)alloc(T * 2304 * 2);
  bf16* vt    = (bf16*)alloc((size_t)48 * 64 * 1024 * 2);
  bf16* sa    = (bf16*)alloc(T * 768 * 2);
  float* x1   = (float*)alloc(T * 768 * 4);
  bf16* yln   = (bf16*)alloc(T * 768 * 2);
  bf16* xn2   = (bf16*)alloc(T * 768 * 2);
  bf16* cqf   = (bf16*)alloc(T * 768 * 2);
  bf16* ckv   = (bf16*)alloc(T * 1536 * 2);
  bf16* cvtT  = (bf16*)alloc((size_t)48 * 64 * 1024 * 2);
  bf16* biasA = (bf16*)alloc((size_t)4 * 1024 * 12 * 1024 * 2);  // [b][q][h][k]
  bf16* ca    = (bf16*)alloc(T * 768 * 2);
  float* x2   = (float*)alloc(T * 768 * 4);
  bf16* xn3   = (bf16*)alloc(T * 768 * 2);
  bf16* hbuf  = (bf16*)alloc(T * 3072 * 2);

  // deferred cvt table: ap, pk, pv, pq, cp, f1, f2 (f32x4 chunk counts)
  AuxArgs aux;
  {
    const float* srcs[7] = {apw, pkw, pvw, pqw, cpw, f1w, f2w};
    bf16* dsts[7] = {w_ap, w_pkv, w_pkv + 768 * 768, w_pq, w_cp, w_f1, w_f2};
    const int n4s[7] = {147456, 147456, 147456, 147456, 147456, 589824, 589824};
    int cum = 0;
    for (int j = 0; j < 7; ++j) {
      aux.csrc[j] = srcs[j]; aux.cdst[j] = dsts[j];
      cum += n4s[j]; aux.cend[j] = cum;
    }
    aux.y = y; aux.gy = lnyg; aux.byv = lnyb; aux.yln = yln;
    aux.sim = sim; aux.mask = mask; aux.biasOut = biasA;
  }

  // D1: qkv cvt + ln(x)   (everything D2 needs)
  prep_k<<<1456, 256, 0, stream>>>(qkvw, w_qkv, x, ln1g, ln1b, xn);

  // D2: qkv GEMM (+V transpose) + aux{ln(y), cvt ap/pk/pv} + bias [0,800)
  AuxArgs a2 = aux;
  a2.extraStart = 0;    a2.extraCount = 1456;   // 1024 lny + 432 cvt(ap,pk,pv)
  a2.biasStart = 0;     a2.biasCount = 800;
  gemm_bt<128,128,false,false,false,true,true><<<576 + 2256, 256, 0, stream>>>(
      xn, w_qkv, nullptr, nullptr, qkvo, nullptr, vt, 1536, 4, 2304, 768,
      576, a2);

  // D3: self-attention + aux{cvt pq/cp/f1/f2} + bias [800,1600)
  AuxArgs a3 = aux;
  a3.extraStart = 1456; a3.extraCount = 1440;   // cvt blocks 432..1872
  a3.biasStart = 800;   a3.biasCount = 800;
  fattn_k<0><<<768 + 2240, 256, 0, stream>>>(
      qkvo, 2304, qkvo + 768, 2304, vt, nullptr, sa, 768, a3);

  // D4: aproj + pkv + bias [1600,3300)
  AuxArgs a4 = aux;
  a4.extraStart = 0;    a4.extraCount = 0;
  a4.biasStart = 1600;  a4.biasCount = 1700;
  apkv_k<<<768 + 1700, 256, 0, stream>>>(sa, w_ap, apb, x, x1,
                                         yln, w_pkv, ckv, cvtT, a4);

  // D5: ln2
  ln_k<<<1024, 256, 0, stream>>>(x1, ln2g, ln2b, xn2);

  // D6: pq + bias [3300,4096)
  AuxArgs a6 = aux;
  a6.extraStart = 0;    a6.extraCount = 0;
  a6.biasStart = 3300;  a6.biasCount = 796;
  gemm_bt<64,128,false,false,false,true,false><<<384 + 796, 256, 0, stream>>>(
      xn2, w_pq, nullptr, nullptr, cqf, nullptr, nullptr, 0, 8, 768, 768,
      384, a6);

  // D7: cross-attention
  AuxArgs a0 = aux;
  a0.extraStart = 0; a0.extraCount = 0; a0.biasStart = 0; a0.biasCount = 0;
  fattn_k<1><<<768, 256, 0, stream>>>(
      cqf, 768, ckv, 1536, cvtT, biasA, ca, 768, a0);

  // D8: cproj
  gemm_bt<64,128,true,false,true,false,false><<<384, 256, 0, stream>>>(
      ca, w_cp, cpb, x1, nullptr, x2, nullptr, 0, 8, 768, 768,
      384, a0);

  // D9: ln3
  ln_k<<<1024, 256, 0, stream>>>(x2, ln3g, ln3b, xn3);

  // D10: fc1
  gemm_bt<128,128,true,true,false,true,false><<<768, 256, 0, stream>>>(
      xn3, w_f1, f1b, nullptr, hbuf, nullptr, nullptr, 0, 4, 3072, 768,
      768, a0);

  // D11: fc2 + y passthrough copy
  fc2copy_k<<<896, 256, 0, stream>>>(
      hbuf, w_f2, f2b, x2, (float*)d_out, y, (float*)d_out + 3145728);
}